// Round 5
// baseline (385.578 us; speedup 1.0000x reference)
//
#include <hip/hip_runtime.h>
#include <hip/hip_cooperative_groups.h>
#include <math.h>

namespace cg = cooperative_groups;

// Problem: x (B=2, C=64, T=16, H=128, W=128) fp32; w (1,2,7,7,7) fp32.
// out = sigmoid(conv3d(concat[max_c(x), mean_c(x)], w, pad=3)) * x
//
// R6 structure (resubmitted R7 — prior round's bench timed out, never ran):
// ONE cooperative kernel (512 blocks x 256 thr, 2 blocks/CU).
//   Phase 1: channel max+mean pool -> pmax|pavg in ws  (each thread 1 float4)
//   grid.sync()
//   Phase 2: 7x7x7 conv over pooled (LDS per-plane, stride-40 aligned rows,
//            fixed-trip unroll-12 staging) + sigmoid in regs, then stream all
//            64 channels: out = attn * x with non-temporal stores.
// Why: R3-R5 showed both separate kernels run < 79 us each (never in top-5;
// poison fills at ~80 us dominate) yet measured region is ~267 us -> the
// excess is boundary/serialization + fill time, not kernel-interior time.
// Merging removes the boundary AND surfaces our kernel in the top-5 counters.
// Fallback: verified 2-kernel path if cooperative launch is unavailable.

#define NP (2 * 16 * 128 * 128) // 524288 pooled points per channel

typedef float vfloat4 __attribute__((ext_vector_type(4)));
typedef float vfloat2 __attribute__((ext_vector_type(2)));

// ------------------------- Fused cooperative kernel -------------------------
__global__ __launch_bounds__(256) void fused_kernel(const float* __restrict__ x,
                                                    const float* __restrict__ wgt,
                                                    float* __restrict__ out,
                                                    float* __restrict__ pooled) { // pmax | pavg contiguous
    __shared__ __align__(16) float sm[2 * 38 * 40]; // 12160 B

    int tid = threadIdx.x;
    int bid = blockIdx.x;

    // ---------------- Phase 1: pool (1 float4 per thread) ----------------
    {
        int j = bid * 256 + tid;        // float4 index in pooled space, [0, 131072)
        int jb = j >> 16;               // batch
        int rest = j & 65535;
        const float4* x4 = (const float4*)x;
        int base = (jb << 22) | rest;   // float4 index into x for c=0

        float4 v = x4[base];
        float4 vmax = v;
        float4 vsum = v;
#pragma unroll 8
        for (int c = 1; c < 64; ++c) {
            float4 u = x4[base + (c << 16)];
            vmax.x = fmaxf(vmax.x, u.x);
            vmax.y = fmaxf(vmax.y, u.y);
            vmax.z = fmaxf(vmax.z, u.z);
            vmax.w = fmaxf(vmax.w, u.w);
            vsum.x += u.x; vsum.y += u.y; vsum.z += u.z; vsum.w += u.w;
        }
        const float s = 1.0f / 64.0f;
        float4 vavg; vavg.x = vsum.x * s; vavg.y = vsum.y * s; vavg.z = vsum.z * s; vavg.w = vsum.w * s;
        ((float4*)pooled)[j] = vmax;
        ((float4*)(pooled + NP))[j] = vavg;
    }

    __threadfence(); // device-scope visibility of pooled across XCDs
    cg::this_grid().sync();

    // ---------------- Phase 2: conv + sigmoid + broadcast multiply --------
    int tw0 = (bid & 3) << 5;
    int th0 = ((bid >> 2) & 3) << 5;
    int t = (bid >> 4) & 15;
    int b = bid >> 8;

    int ty = tid >> 3;         // 0..31 output row within tile
    int txg = (tid & 7) << 2;  // 0,4,...,28 output col group (4 consecutive w)

    // float4 index: b*2^22 + c*2^16 + t*2^12 + gh*2^5 + gw/4
    int base4 = (b << 22) + (t << 12) + ((th0 + ty) << 5) + ((tw0 + txg) >> 2);
    int cs = bid & 63; // per-block channel stagger
    const vfloat4* x4 = (const vfloat4*)x;
    vfloat4* o4 = (vfloat4*)out;

    // Prefetch 16 staggered channels of x: loads fly during the conv phase.
    vfloat4 pre[16];
#pragma unroll
    for (int k = 0; k < 16; ++k)
        pre[k] = x4[base4 + (((cs + k) & 63) << 16)];

    float acc0 = 0.f, acc1 = 0.f, acc2 = 0.f, acc3 = 0.f;

    for (int dz = 0; dz < 7; ++dz) {
        int tsrc = t + dz - 3;
        if (tsrc < 0 || tsrc >= 16) continue; // block-uniform: barriers stay uniform

        __syncthreads(); // protect LDS from previous plane's readers
        // Fixed-trip staging: 12 predicated iterations, all loads independent.
#pragma unroll
        for (int r = 0; r < 12; ++r) {
            int i = tid + (r << 8);
            int ch = i / 1444;
            int rem = i - ch * 1444;
            int y = rem / 38;
            int xx = rem - y * 38;
            int gh = th0 + y - 3;
            int gw = tw0 + xx - 3;
            float val = 0.f;
            if (i < 2888 && (unsigned)gh < 128u && (unsigned)gw < 128u)
                val = pooled[ch * NP + (((b << 4) + tsrc) << 14) + (gh << 7) + gw];
            if (i < 2888)
                sm[ch * 1520 + y * 40 + xx] = val;
        }
        __syncthreads();

        const float* wdz = wgt + dz * 49;
#pragma unroll
        for (int ch = 0; ch < 2; ++ch) {
#pragma unroll
            for (int dy = 0; dy < 7; ++dy) {
                const float* rp = &sm[ch * 1520 + (ty + dy) * 40 + txg];
                vfloat4 r0 = *(const vfloat4*)rp;        // row[0..3]  (16B-aligned)
                vfloat4 r1 = *(const vfloat4*)(rp + 4);  // row[4..7]
                vfloat2 r2 = *(const vfloat2*)(rp + 8);  // row[8..9]
                float row[10] = {r0.x, r0.y, r0.z, r0.w,
                                 r1.x, r1.y, r1.z, r1.w,
                                 r2.x, r2.y};
                const float* wr = wdz + ch * 343 + dy * 7;
#pragma unroll
                for (int dx = 0; dx < 7; ++dx) {
                    float wv = wr[dx];
                    acc0 = fmaf(wv, row[dx + 0], acc0);
                    acc1 = fmaf(wv, row[dx + 1], acc1);
                    acc2 = fmaf(wv, row[dx + 2], acc2);
                    acc3 = fmaf(wv, row[dx + 3], acc3);
                }
            }
        }
    }

    vfloat4 av;
    av.x = 1.f / (1.f + __expf(-acc0));
    av.y = 1.f / (1.f + __expf(-acc1));
    av.z = 1.f / (1.f + __expf(-acc2));
    av.w = 1.f / (1.f + __expf(-acc3));

    // out[b, c, t, gh, gw..gw+3] = attn * x for all 64 channels (staggered).
#pragma unroll
    for (int k = 0; k < 16; ++k) {
        int idx = base4 + (((cs + k) & 63) << 16);
        __builtin_nontemporal_store(pre[k] * av, &o4[idx]);
    }
#pragma unroll 8
    for (int k = 16; k < 64; ++k) {
        int idx = base4 + (((cs + k) & 63) << 16);
        vfloat4 xv = x4[idx];
        __builtin_nontemporal_store(xv * av, &o4[idx]);
    }
}

// --------------------- Fallback: verified 2-kernel path ---------------------
__global__ __launch_bounds__(256) void pool_kernel(const float* __restrict__ x,
                                                   float* __restrict__ pmax,
                                                   float* __restrict__ pavg) {
    int j = blockIdx.x * 256 + threadIdx.x;
    int b = j >> 16;
    int rest = j & 65535;
    const float4* x4 = (const float4*)x;
    int base = (b << 22) | rest;

    float4 v = x4[base];
    float4 vmax = v;
    float4 vsum = v;
#pragma unroll 8
    for (int c = 1; c < 64; ++c) {
        float4 u = x4[base + (c << 16)];
        vmax.x = fmaxf(vmax.x, u.x);
        vmax.y = fmaxf(vmax.y, u.y);
        vmax.z = fmaxf(vmax.z, u.z);
        vmax.w = fmaxf(vmax.w, u.w);
        vsum.x += u.x; vsum.y += u.y; vsum.z += u.z; vsum.w += u.w;
    }
    const float s = 1.0f / 64.0f;
    float4 vavg; vavg.x = vsum.x * s; vavg.y = vsum.y * s; vavg.z = vsum.z * s; vavg.w = vsum.w * s;
    ((float4*)pmax)[j] = vmax;
    ((float4*)pavg)[j] = vavg;
}

__global__ __launch_bounds__(256) void conv_mul_kernel(const float* __restrict__ pooled,
                                                       const float* __restrict__ wgt,
                                                       const float* __restrict__ x,
                                                       float* __restrict__ out) {
    __shared__ __align__(16) float sm[2 * 38 * 40];

    int bid = blockIdx.x;
    int tw0 = (bid & 3) << 5;
    int th0 = ((bid >> 2) & 3) << 5;
    int t = (bid >> 4) & 15;
    int b = bid >> 8;

    int tid = threadIdx.x;
    int ty = tid >> 3;
    int txg = (tid & 7) << 2;

    int base4 = (b << 22) + (t << 12) + ((th0 + ty) << 5) + ((tw0 + txg) >> 2);
    int cs = bid & 63;
    const vfloat4* x4 = (const vfloat4*)x;
    vfloat4* o4 = (vfloat4*)out;

    vfloat4 pre[16];
#pragma unroll
    for (int k = 0; k < 16; ++k)
        pre[k] = x4[base4 + (((cs + k) & 63) << 16)];

    float acc0 = 0.f, acc1 = 0.f, acc2 = 0.f, acc3 = 0.f;

    for (int dz = 0; dz < 7; ++dz) {
        int tsrc = t + dz - 3;
        if (tsrc < 0 || tsrc >= 16) continue;

        __syncthreads();
#pragma unroll
        for (int r = 0; r < 12; ++r) {
            int i = tid + (r << 8);
            int ch = i / 1444;
            int rem = i - ch * 1444;
            int y = rem / 38;
            int xx = rem - y * 38;
            int gh = th0 + y - 3;
            int gw = tw0 + xx - 3;
            float val = 0.f;
            if (i < 2888 && (unsigned)gh < 128u && (unsigned)gw < 128u)
                val = pooled[ch * NP + (((b << 4) + tsrc) << 14) + (gh << 7) + gw];
            if (i < 2888)
                sm[ch * 1520 + y * 40 + xx] = val;
        }
        __syncthreads();

        const float* wdz = wgt + dz * 49;
#pragma unroll
        for (int ch = 0; ch < 2; ++ch) {
#pragma unroll
            for (int dy = 0; dy < 7; ++dy) {
                const float* rp = &sm[ch * 1520 + (ty + dy) * 40 + txg];
                vfloat4 r0 = *(const vfloat4*)rp;
                vfloat4 r1 = *(const vfloat4*)(rp + 4);
                vfloat2 r2 = *(const vfloat2*)(rp + 8);
                float row[10] = {r0.x, r0.y, r0.z, r0.w,
                                 r1.x, r1.y, r1.z, r1.w,
                                 r2.x, r2.y};
                const float* wr = wdz + ch * 343 + dy * 7;
#pragma unroll
                for (int dx = 0; dx < 7; ++dx) {
                    float wv = wr[dx];
                    acc0 = fmaf(wv, row[dx + 0], acc0);
                    acc1 = fmaf(wv, row[dx + 1], acc1);
                    acc2 = fmaf(wv, row[dx + 2], acc2);
                    acc3 = fmaf(wv, row[dx + 3], acc3);
                }
            }
        }
    }

    vfloat4 av;
    av.x = 1.f / (1.f + __expf(-acc0));
    av.y = 1.f / (1.f + __expf(-acc1));
    av.z = 1.f / (1.f + __expf(-acc2));
    av.w = 1.f / (1.f + __expf(-acc3));

#pragma unroll
    for (int k = 0; k < 16; ++k) {
        int idx = base4 + (((cs + k) & 63) << 16);
        __builtin_nontemporal_store(pre[k] * av, &o4[idx]);
    }
#pragma unroll 8
    for (int k = 16; k < 64; ++k) {
        int idx = base4 + (((cs + k) & 63) << 16);
        vfloat4 xv = x4[idx];
        __builtin_nontemporal_store(xv * av, &o4[idx]);
    }
}

extern "C" void kernel_launch(void* const* d_in, const int* in_sizes, int n_in,
                              void* d_out, int out_size, void* d_ws, size_t ws_size,
                              hipStream_t stream) {
    const float* x = (const float*)d_in[0];
    const float* w = (const float*)d_in[1];
    float* out = (float*)d_out;
    float* ws = (float*)d_ws;

    float* pmax = ws;       // NP floats
    float* pavg = ws + NP;  // NP floats (contiguous after pmax: conv indexes ch*NP)
    (void)pavg;

    // Single cooperative kernel: 512 blocks (2/CU), grid.sync between phases.
    void* args[] = {(void*)&x, (void*)&w, (void*)&out, (void*)&pmax};
    hipError_t err = hipLaunchCooperativeKernel((void*)fused_kernel,
                                                dim3(512), dim3(256),
                                                args, 0, stream);
    if (err != hipSuccess) {
        // Fallback: verified 2-kernel path.
        pool_kernel<<<NP / 4 / 256, 256, 0, stream>>>(x, pmax, ws + NP);
        conv_mul_kernel<<<2 * 16 * 4 * 4, 256, 0, stream>>>(pmax, w, x, out);
    }
}

// Round 9
// 320.906 us; speedup vs baseline: 1.2015x; 1.2015x over previous
//
#include <hip/hip_runtime.h>
#include <math.h>

// Problem: x (B=2, C=64, T=16, H=128, W=128) fp32; w (1,2,7,7,7) fp32.
// out = sigmoid(conv3d(concat[max_c(x), mean_c(x)], w, pad=3)) * x
//
// R8 structure (resubmitted R11 — rounds 6, 7, 8 all hit GPU-acquisition
// timeouts; this source has never been benched):
// 2 kernels, channel-split conv_mul.
// Evidence (R5-coop probe): timed region = ~160 us fixed harness fills +
// our kernels (~106 us in the best 2-kernel run). Coop fusion regressed our
// part to 216 us at 22.6% occupancy / 5% VALUBusy -> latency-bound, grid-
// limited (2 blocks/CU). FETCH=136 MB showed the streaming x-read is fully
// L3-served, so K2's HBM floor is only the 134 MB write (~20 us); its ~78 us
// was concurrency-starved, not BW- or instruction-bound.
// Fix: K2 at 2048 blocks -- 4 blocks per 32x32 tile, each redundantly
// computes the cheap conv, streams a disjoint 16-channel slice. All 16
// float4 x-values prefetched (L3-hot) during conv; stream phase = pure
// nt-stores. No lockstep: conv of one block overlaps streaming of others.
//   K1 pool:      x (128 MiB) -> pmax|pavg (4 MiB)      [HBM-bound, ~21 us]
//   K2 conv+mul:  2048 blocks, conv (LDS per-plane, stride-40, unroll-12
//                 staging) + sigmoid + 16-channel nt-store stream.

#define NP (2 * 16 * 128 * 128) // 524288 pooled points per channel

typedef float vfloat4 __attribute__((ext_vector_type(4)));
typedef float vfloat2 __attribute__((ext_vector_type(2)));

// ---------------- Kernel 1: channel max + mean pool (float4) ----------------
__global__ __launch_bounds__(256) void pool_kernel(const float* __restrict__ x,
                                                   float* __restrict__ pmax,
                                                   float* __restrict__ pavg) {
    int j = blockIdx.x * 256 + threadIdx.x; // float4 index in pooled space, [0, 131072)
    int b = j >> 16;                        // 65536 float4 per batch in pooled space
    int rest = j & 65535;
    const float4* x4 = (const float4*)x;
    int base = (b << 22) | rest;            // float4 index into x for c=0

    float4 v = x4[base];
    float4 vmax = v;
    float4 vsum = v;
#pragma unroll 8
    for (int c = 1; c < 64; ++c) {
        float4 u = x4[base + (c << 16)];
        vmax.x = fmaxf(vmax.x, u.x);
        vmax.y = fmaxf(vmax.y, u.y);
        vmax.z = fmaxf(vmax.z, u.z);
        vmax.w = fmaxf(vmax.w, u.w);
        vsum.x += u.x; vsum.y += u.y; vsum.z += u.z; vsum.w += u.w;
    }
    const float s = 1.0f / 64.0f;
    float4 vavg; vavg.x = vsum.x * s; vavg.y = vsum.y * s; vavg.z = vsum.z * s; vavg.w = vsum.w * s;
    ((float4*)pmax)[j] = vmax;
    ((float4*)pavg)[j] = vavg;
}

// ------ Kernel 2: 7x7x7 conv (2ch) + sigmoid + 16-channel multiply ----------
// 2048 blocks. bid = [b(1) | t(4) | th(2) | tw(2) | g(2)]. The 4 blocks with
// the same (b,t,th,tw) each compute the same conv for the 32x32 tile
// (redundant, cheap) and stream disjoint channels c = g*16 .. g*16+15.
// LDS stages one dz-plane of the 2-channel pooled halo: 2 x 38 x 40 floats
// (stride 40 keeps each thread's 10-wide row 16B-aligned).
__global__ __launch_bounds__(256) void conv_mul_kernel(const float* __restrict__ pooled, // pmax | pavg contiguous
                                                       const float* __restrict__ wgt,    // (1,2,7,7,7)
                                                       const float* __restrict__ x,
                                                       float* __restrict__ out) {
    __shared__ __align__(16) float sm[2 * 38 * 40]; // 12160 B

    int bid = blockIdx.x;
    int g   = bid & 3;               // channel group
    int tw0 = ((bid >> 2) & 3) << 5;
    int th0 = ((bid >> 4) & 3) << 5;
    int t   = (bid >> 6) & 15;
    int b   = bid >> 10;

    int tid = threadIdx.x;
    int ty = tid >> 3;         // 0..31 output row within tile
    int txg = (tid & 7) << 2;  // 0,4,...,28 output col group (4 consecutive w)

    // float4 index: b*2^22 + c*2^16 + t*2^12 + gh*2^5 + gw/4
    int base4 = (b << 22) + (t << 12) + ((th0 + ty) << 5) + ((tw0 + txg) >> 2);
    int c0 = g << 4; // first channel of this block's 16-channel slice
    const vfloat4* x4 = (const vfloat4*)x;
    vfloat4* o4 = (vfloat4*)out;

    // Prefetch ALL 16 of this block's channels (L3-hot after K1): loads fly
    // during the conv phase; stream phase is then pure stores.
    vfloat4 pre[16];
#pragma unroll
    for (int k = 0; k < 16; ++k)
        pre[k] = x4[base4 + ((c0 + k) << 16)];

    float acc0 = 0.f, acc1 = 0.f, acc2 = 0.f, acc3 = 0.f;

    for (int dz = 0; dz < 7; ++dz) {
        int tsrc = t + dz - 3;
        if (tsrc < 0 || tsrc >= 16) continue; // block-uniform: barriers stay uniform

        __syncthreads(); // protect LDS from previous plane's readers
        // Fixed-trip staging: 12 predicated iterations, all loads independent.
#pragma unroll
        for (int r = 0; r < 12; ++r) {
            int i = tid + (r << 8);
            int ch = i / 1444;
            int rem = i - ch * 1444;
            int y = rem / 38;
            int xx = rem - y * 38;
            int gh = th0 + y - 3;
            int gw = tw0 + xx - 3;
            float val = 0.f;
            if (i < 2888 && (unsigned)gh < 128u && (unsigned)gw < 128u)
                val = pooled[ch * NP + (((b << 4) + tsrc) << 14) + (gh << 7) + gw];
            if (i < 2888)
                sm[ch * 1520 + y * 40 + xx] = val;
        }
        __syncthreads();

        const float* wdz = wgt + dz * 49;
#pragma unroll
        for (int ch = 0; ch < 2; ++ch) {
#pragma unroll
            for (int dy = 0; dy < 7; ++dy) {
                const float* rp = &sm[ch * 1520 + (ty + dy) * 40 + txg];
                vfloat4 r0 = *(const vfloat4*)rp;        // row[0..3]  (16B-aligned)
                vfloat4 r1 = *(const vfloat4*)(rp + 4);  // row[4..7]
                vfloat2 r2 = *(const vfloat2*)(rp + 8);  // row[8..9]
                float row[10] = {r0.x, r0.y, r0.z, r0.w,
                                 r1.x, r1.y, r1.z, r1.w,
                                 r2.x, r2.y};
                const float* wr = wdz + ch * 343 + dy * 7;
#pragma unroll
                for (int dx = 0; dx < 7; ++dx) {
                    float wv = wr[dx];
                    acc0 = fmaf(wv, row[dx + 0], acc0);
                    acc1 = fmaf(wv, row[dx + 1], acc1);
                    acc2 = fmaf(wv, row[dx + 2], acc2);
                    acc3 = fmaf(wv, row[dx + 3], acc3);
                }
            }
        }
    }

    vfloat4 av;
    av.x = 1.f / (1.f + __expf(-acc0));
    av.y = 1.f / (1.f + __expf(-acc1));
    av.z = 1.f / (1.f + __expf(-acc2));
    av.w = 1.f / (1.f + __expf(-acc3));

    // Stream phase: pure non-temporal stores of this block's 16 channels.
#pragma unroll
    for (int k = 0; k < 16; ++k) {
        int idx = base4 + ((c0 + k) << 16);
        __builtin_nontemporal_store(pre[k] * av, &o4[idx]);
    }
}

extern "C" void kernel_launch(void* const* d_in, const int* in_sizes, int n_in,
                              void* d_out, int out_size, void* d_ws, size_t ws_size,
                              hipStream_t stream) {
    const float* x = (const float*)d_in[0];
    const float* w = (const float*)d_in[1];
    float* out = (float*)d_out;
    float* ws = (float*)d_ws;

    float* pmax = ws;       // NP floats
    float* pavg = ws + NP;  // NP floats (must follow pmax: conv indexes ch*NP)

    pool_kernel<<<NP / 4 / 256, 256, 0, stream>>>(x, pmax, pavg);
    conv_mul_kernel<<<2 * 16 * 4 * 4 * 4, 256, 0, stream>>>(pmax, w, x, out);
}

// Round 11
// 265.975 us; speedup vs baseline: 1.4497x; 1.2065x over previous
//
#include <hip/hip_runtime.h>
#include <math.h>

// Problem: x (B=2, C=64, T=16, H=128, W=128) fp32; w (1,2,7,7,7) fp32.
// out = sigmoid(conv3d(concat[max_c(x), mean_c(x)], w, pad=3)) * x
//
// R12 structure (resubmitted R13 — round 10 hit a GPU-acquisition timeout;
// this source has never been benched):
// fused 2-kernel (best measured: 266.7 us), stream phase restructured into
// 16-deep load-then-store chunks.
// Evidence ledger:
//   - R5-coop probe: timed region = ~165 us fixed harness fills + kernels.
//     FETCH=136 MB -> stream x-read is L3-served. nt stores protect x in L3.
//   - R9 channel-split: conv x4 redundancy = +42 us (conv ~ 14 us per 1x);
//     occupancy did NOT rise with 4x blocks (20%); stream gained nothing.
//     => fused K2 (78 us) = ~14 conv + ~60 stream; STREAM is the target.
//   - pool_kernel saturates 6.5 TB/s with the SAME 1-MiB-stride pattern and
//     same 8 waves/CU, but load-only. Stream's 1:1 load->nt-store interleave
//     shares the vmcnt queue -> consumer waits sit behind HBM store
//     retirement -> ~2 TB/s. Fix: batch {16 loads} then {16 stores} per
//     chunk, sched_barrier(0) between, so 16 loads are always in flight and
//     stores never gate the next chunk's loads.
//   K1 pool:      x (128 MiB) -> pmax|pavg (4 MiB)   [6.5 TB/s, ~21 us]
//   K2 conv+mul:  conv3d (LDS per-plane, stride-40, unroll-12 staging) +
//                 sigmoid in regs + chunked 64-channel stream, nt stores.

#define NP (2 * 16 * 128 * 128) // 524288 pooled points per channel

typedef float vfloat4 __attribute__((ext_vector_type(4)));
typedef float vfloat2 __attribute__((ext_vector_type(2)));

// ---------------- Kernel 1: channel max + mean pool (float4) ----------------
__global__ __launch_bounds__(256) void pool_kernel(const float* __restrict__ x,
                                                   float* __restrict__ pmax,
                                                   float* __restrict__ pavg) {
    int j = blockIdx.x * 256 + threadIdx.x; // float4 index in pooled space, [0, 131072)
    int b = j >> 16;                        // 65536 float4 per batch in pooled space
    int rest = j & 65535;
    const float4* x4 = (const float4*)x;
    int base = (b << 22) | rest;            // float4 index into x for c=0

    float4 v = x4[base];
    float4 vmax = v;
    float4 vsum = v;
#pragma unroll 8
    for (int c = 1; c < 64; ++c) {
        float4 u = x4[base + (c << 16)];
        vmax.x = fmaxf(vmax.x, u.x);
        vmax.y = fmaxf(vmax.y, u.y);
        vmax.z = fmaxf(vmax.z, u.z);
        vmax.w = fmaxf(vmax.w, u.w);
        vsum.x += u.x; vsum.y += u.y; vsum.z += u.z; vsum.w += u.w;
    }
    const float s = 1.0f / 64.0f;
    float4 vavg; vavg.x = vsum.x * s; vavg.y = vsum.y * s; vavg.z = vsum.z * s; vavg.w = vsum.w * s;
    ((float4*)pmax)[j] = vmax;
    ((float4*)pavg)[j] = vavg;
}

// -------- Kernel 2: 7x7x7 conv (2ch) + sigmoid + chunked multiply -----------
// Block = 256 threads handles one (b, t) and a 32x32 (h,w) tile.
// LDS stages one dz-plane of the 2-channel pooled halo: 2 x 38 x 40 floats
// (stride 40 keeps each thread's 10-wide row 16B-aligned).
// Each thread computes attn for its own 4 consecutive-w pixels, keeps them in
// registers, then streams all 64 channels of x in 16-deep chunks.
__global__ __launch_bounds__(256) void conv_mul_kernel(const float* __restrict__ pooled, // pmax | pavg contiguous
                                                       const float* __restrict__ wgt,    // (1,2,7,7,7)
                                                       const float* __restrict__ x,
                                                       float* __restrict__ out) {
    __shared__ __align__(16) float sm[2 * 38 * 40]; // 12160 B

    int bid = blockIdx.x;
    int tw0 = (bid & 3) << 5;
    int th0 = ((bid >> 2) & 3) << 5;
    int t = (bid >> 4) & 15;
    int b = bid >> 8;

    int tid = threadIdx.x;
    int ty = tid >> 3;         // 0..31 output row within tile
    int txg = (tid & 7) << 2;  // 0,4,...,28 output col group (4 consecutive w)

    // float4 index: b*2^22 + c*2^16 + t*2^12 + gh*2^5 + gw/4
    int base4 = (b << 22) + (t << 12) + ((th0 + ty) << 5) + ((tw0 + txg) >> 2);
    int cs = bid & 63; // per-block channel stagger
    const vfloat4* x4 = (const vfloat4*)x;
    vfloat4* o4 = (vfloat4*)out;

    // Prefetch chunk 0 (16 staggered channels): loads fly during the conv
    // phase; data parks in VGPRs until the streaming phase.
    vfloat4 pre[16];
#pragma unroll
    for (int k = 0; k < 16; ++k)
        pre[k] = x4[base4 + (((cs + k) & 63) << 16)];

    float acc0 = 0.f, acc1 = 0.f, acc2 = 0.f, acc3 = 0.f;

    for (int dz = 0; dz < 7; ++dz) {
        int tsrc = t + dz - 3;
        if (tsrc < 0 || tsrc >= 16) continue; // block-uniform: barriers stay uniform

        __syncthreads(); // protect LDS from previous plane's readers
        // Fixed-trip staging: 12 predicated iterations, all loads independent.
#pragma unroll
        for (int r = 0; r < 12; ++r) {
            int i = tid + (r << 8);
            int ch = i / 1444;
            int rem = i - ch * 1444;
            int y = rem / 38;
            int xx = rem - y * 38;
            int gh = th0 + y - 3;
            int gw = tw0 + xx - 3;
            float val = 0.f;
            if (i < 2888 && (unsigned)gh < 128u && (unsigned)gw < 128u)
                val = pooled[ch * NP + (((b << 4) + tsrc) << 14) + (gh << 7) + gw];
            if (i < 2888)
                sm[ch * 1520 + y * 40 + xx] = val;
        }
        __syncthreads();

        const float* wdz = wgt + dz * 49;
#pragma unroll
        for (int ch = 0; ch < 2; ++ch) {
#pragma unroll
            for (int dy = 0; dy < 7; ++dy) {
                const float* rp = &sm[ch * 1520 + (ty + dy) * 40 + txg];
                vfloat4 r0 = *(const vfloat4*)rp;        // row[0..3]  (16B-aligned)
                vfloat4 r1 = *(const vfloat4*)(rp + 4);  // row[4..7]
                vfloat2 r2 = *(const vfloat2*)(rp + 8);  // row[8..9]
                float row[10] = {r0.x, r0.y, r0.z, r0.w,
                                 r1.x, r1.y, r1.z, r1.w,
                                 r2.x, r2.y};
                const float* wr = wdz + ch * 343 + dy * 7;
#pragma unroll
                for (int dx = 0; dx < 7; ++dx) {
                    float wv = wr[dx];
                    acc0 = fmaf(wv, row[dx + 0], acc0);
                    acc1 = fmaf(wv, row[dx + 1], acc1);
                    acc2 = fmaf(wv, row[dx + 2], acc2);
                    acc3 = fmaf(wv, row[dx + 3], acc3);
                }
            }
        }
    }

    vfloat4 av;
    av.x = 1.f / (1.f + __expf(-acc0));
    av.y = 1.f / (1.f + __expf(-acc1));
    av.z = 1.f / (1.f + __expf(-acc2));
    av.w = 1.f / (1.f + __expf(-acc3));

    // Stream phase, chunked: {16 loads} -> sched_barrier -> {16 mul+nt-store}.
    // Loads of a chunk are all in flight together; stores retire behind the
    // next chunk's loads without gating them (vmcnt waits only count down to
    // the needed load). Chunk 0 was prefetched before the conv.
#pragma unroll
    for (int k = 0; k < 16; ++k) {
        int idx = base4 + (((cs + k) & 63) << 16);
        __builtin_nontemporal_store(pre[k] * av, &o4[idx]);
    }
    for (int cch = 1; cch < 4; ++cch) { // not unrolled: buf reused, VGPR capped
        vfloat4 buf[16];
#pragma unroll
        for (int k = 0; k < 16; ++k)
            buf[k] = x4[base4 + (((cs + (cch << 4) + k) & 63) << 16)];
        __builtin_amdgcn_sched_barrier(0); // pin: all 16 loads issue before stores
#pragma unroll
        for (int k = 0; k < 16; ++k) {
            int idx = base4 + (((cs + (cch << 4) + k) & 63) << 16);
            __builtin_nontemporal_store(buf[k] * av, &o4[idx]);
        }
    }
}

extern "C" void kernel_launch(void* const* d_in, const int* in_sizes, int n_in,
                              void* d_out, int out_size, void* d_ws, size_t ws_size,
                              hipStream_t stream) {
    const float* x = (const float*)d_in[0];
    const float* w = (const float*)d_in[1];
    float* out = (float*)d_out;
    float* ws = (float*)d_ws;

    float* pmax = ws;       // NP floats
    float* pavg = ws + NP;  // NP floats (must follow pmax: conv indexes ch*NP)

    pool_kernel<<<NP / 4 / 256, 256, 0, stream>>>(x, pmax, pavg);
    conv_mul_kernel<<<2 * 16 * 4 * 4, 256, 0, stream>>>(pmax, w, x, out);
}

// Round 13
// 265.604 us; speedup vs baseline: 1.4517x; 1.0014x over previous
//
#include <hip/hip_runtime.h>
#include <math.h>

// Problem: x (B=2, C=64, T=16, H=128, W=128) fp32; w (1,2,7,7,7) fp32.
// out = sigmoid(conv3d(concat[max_c(x), mean_c(x)], w, pad=3)) * x
//
// R14 structure (resubmitted R15 — round 12 hit a GPU-acquisition timeout;
// this source has never been benched):
// fused 2-kernel, K2 retiled to 8x128 strips so every global access is
// WAVE-LINEAR (1 KiB contiguous per wave).
// Evidence ledger:
//   - ~170 us of the timed region is fixed harness fills (R5 coop probe).
//   - R9: conv ~14 us; stream ~60 us is the target. More blocks didn't help.
//   - R12: load/store chunking + sched_barrier = flat -> ordering exonerated.
//   - Pattern comparison: fill (linear writes) 6.8 TB/s; pool (linear reads)
//     6.5 TB/s; K2 stream (8x128B segments @512B stride per wave, from the
//     32x32 tile's 8-threads-per-row mapping) ~2 TB/s writes + 60% read
//     L3-miss. The ONLY untested common factor across all slow variants is
//     this striped access shape -> retile so waves cover 2 full image rows.
//   K1 pool:  x (128 MiB) -> pmax|pavg (4 MiB)   [6.5 TB/s, ~21 us]
//   K2:       block = (b, t, 8-row strip) of 128-w; ty=tid>>5, tx=tid&31.
//             Wave = 2 full rows = 64 consecutive float4s for x/out access.
//             Conv identical per thread (4 w-pixels); halo 2x14x134 in LDS
//             (stride 136 keeps 10-wide rows 16B-aligned).

#define NP (2 * 16 * 128 * 128) // 524288 pooled points per channel
#define SMH 14                  // halo rows per plane (8 + 6)
#define SMW 134                 // halo cols (128 + 6)
#define SMSTRIDE 136            // row stride (16B-aligned: 136*4 = 544 = 34*16)
#define SMCH (SMH * SMSTRIDE)   // 1904 floats per channel plane

typedef float vfloat4 __attribute__((ext_vector_type(4)));
typedef float vfloat2 __attribute__((ext_vector_type(2)));

// ---------------- Kernel 1: channel max + mean pool (float4) ----------------
__global__ __launch_bounds__(256) void pool_kernel(const float* __restrict__ x,
                                                   float* __restrict__ pmax,
                                                   float* __restrict__ pavg) {
    int j = blockIdx.x * 256 + threadIdx.x; // float4 index in pooled space, [0, 131072)
    int b = j >> 16;                        // 65536 float4 per batch in pooled space
    int rest = j & 65535;
    const float4* x4 = (const float4*)x;
    int base = (b << 22) | rest;            // float4 index into x for c=0

    float4 v = x4[base];
    float4 vmax = v;
    float4 vsum = v;
#pragma unroll 8
    for (int c = 1; c < 64; ++c) {
        float4 u = x4[base + (c << 16)];
        vmax.x = fmaxf(vmax.x, u.x);
        vmax.y = fmaxf(vmax.y, u.y);
        vmax.z = fmaxf(vmax.z, u.z);
        vmax.w = fmaxf(vmax.w, u.w);
        vsum.x += u.x; vsum.y += u.y; vsum.z += u.z; vsum.w += u.w;
    }
    const float s = 1.0f / 64.0f;
    float4 vavg; vavg.x = vsum.x * s; vavg.y = vsum.y * s; vavg.z = vsum.z * s; vavg.w = vsum.w * s;
    ((float4*)pmax)[j] = vmax;
    ((float4*)pavg)[j] = vavg;
}

// ---- Kernel 2: 7x7x7 conv (2ch) + sigmoid + multiply, 8x128 strip tiles ----
// 512 blocks: bid = [b(1) | t(4) | strip(4)]. Block covers rows
// th0..th0+7, all 128 w. Thread: ty = tid>>5 (row), tx = tid&31 (float4 col),
// owns 4 consecutive w-pixels. Wave = rows {2w, 2w+1} full-width = 1 KiB
// contiguous global accesses.
__global__ __launch_bounds__(256) void conv_mul_kernel(const float* __restrict__ pooled, // pmax | pavg contiguous
                                                       const float* __restrict__ wgt,    // (1,2,7,7,7)
                                                       const float* __restrict__ x,
                                                       float* __restrict__ out) {
    __shared__ __align__(16) float sm[2 * SMCH]; // 15232 B

    int bid = blockIdx.x;
    int strip = bid & 15;
    int t = (bid >> 4) & 15;
    int b = bid >> 8;
    int th0 = strip << 3;

    int tid = threadIdx.x;
    int ty = tid >> 5;        // 0..7 row within strip
    int tx = tid & 31;        // float4 col 0..31

    // float4 index: b*2^22 + c*2^16 + t*2^12 + h*2^5 + w/4
    int base4 = (b << 22) + (t << 12) + ((th0 + ty) << 5) + tx;
    int cs = bid & 63; // per-block channel stagger
    const vfloat4* x4 = (const vfloat4*)x;
    vfloat4* o4 = (vfloat4*)out;

    // Prefetch chunk 0 (16 staggered channels): loads fly during the conv
    // phase; data parks in VGPRs until the streaming phase.
    vfloat4 pre[16];
#pragma unroll
    for (int k = 0; k < 16; ++k)
        pre[k] = x4[base4 + (((cs + k) & 63) << 16)];

    float acc0 = 0.f, acc1 = 0.f, acc2 = 0.f, acc3 = 0.f;

    for (int dz = 0; dz < 7; ++dz) {
        int tsrc = t + dz - 3;
        if (tsrc < 0 || tsrc >= 16) continue; // block-uniform: barriers stay uniform

        __syncthreads(); // protect LDS from previous plane's readers
        // Fixed-trip staging: 15 predicated iterations (2*1904 = 3808 slots),
        // all loads independent. sm is written linearly (sm[i]); cols >= 134
        // are padding and get 0.
#pragma unroll
        for (int r = 0; r < 15; ++r) {
            int i = tid + (r << 8);
            int ch = i / SMCH;
            int rem = i - ch * SMCH;
            int y = rem / SMSTRIDE;
            int xx = rem - y * SMSTRIDE;
            int gh = th0 + y - 3;
            int gw = xx - 3;
            float val = 0.f;
            if (i < 2 * SMCH && xx < SMW && (unsigned)gh < 128u && (unsigned)gw < 128u)
                val = pooled[ch * NP + (((b << 4) + tsrc) << 14) + (gh << 7) + gw];
            if (i < 2 * SMCH)
                sm[i] = val;
        }
        __syncthreads();

        const float* wdz = wgt + dz * 49;
#pragma unroll
        for (int ch = 0; ch < 2; ++ch) {
#pragma unroll
            for (int dy = 0; dy < 7; ++dy) {
                // Output pixels w = tx*4+j (j=0..3); halo col xx = w + dx.
                // Row base: halo offset tx*4, 16B-aligned (stride 544B).
                const float* rp = &sm[ch * SMCH + (ty + dy) * SMSTRIDE + (tx << 2)];
                vfloat4 r0 = *(const vfloat4*)rp;        // xx tx*4+0..3
                vfloat4 r1 = *(const vfloat4*)(rp + 4);  // +4..7
                vfloat2 r2 = *(const vfloat2*)(rp + 8);  // +8..9
                float row[10] = {r0.x, r0.y, r0.z, r0.w,
                                 r1.x, r1.y, r1.z, r1.w,
                                 r2.x, r2.y};
                const float* wr = wdz + ch * 343 + dy * 7;
#pragma unroll
                for (int dx = 0; dx < 7; ++dx) {
                    float wv = wr[dx];
                    acc0 = fmaf(wv, row[dx + 0], acc0);
                    acc1 = fmaf(wv, row[dx + 1], acc1);
                    acc2 = fmaf(wv, row[dx + 2], acc2);
                    acc3 = fmaf(wv, row[dx + 3], acc3);
                }
            }
        }
    }

    vfloat4 av;
    av.x = 1.f / (1.f + __expf(-acc0));
    av.y = 1.f / (1.f + __expf(-acc1));
    av.z = 1.f / (1.f + __expf(-acc2));
    av.w = 1.f / (1.f + __expf(-acc3));

    // Stream phase, chunked: {16 loads} -> {16 mul+nt-store} per chunk.
    // Every access is 1 KiB wave-contiguous now. Chunk 0 prefetched above.
#pragma unroll
    for (int k = 0; k < 16; ++k) {
        int idx = base4 + (((cs + k) & 63) << 16);
        __builtin_nontemporal_store(pre[k] * av, &o4[idx]);
    }
    for (int cch = 1; cch < 4; ++cch) { // not unrolled: buf reused, VGPR capped
        vfloat4 buf[16];
#pragma unroll
        for (int k = 0; k < 16; ++k)
            buf[k] = x4[base4 + (((cs + (cch << 4) + k) & 63) << 16)];
        __builtin_amdgcn_sched_barrier(0); // pin: all 16 loads issue before stores
#pragma unroll
        for (int k = 0; k < 16; ++k) {
            int idx = base4 + (((cs + (cch << 4) + k) & 63) << 16);
            __builtin_nontemporal_store(buf[k] * av, &o4[idx]);
        }
    }
}

extern "C" void kernel_launch(void* const* d_in, const int* in_sizes, int n_in,
                              void* d_out, int out_size, void* d_ws, size_t ws_size,
                              hipStream_t stream) {
    const float* x = (const float*)d_in[0];
    const float* w = (const float*)d_in[1];
    float* out = (float*)d_out;
    float* ws = (float*)d_ws;

    float* pmax = ws;       // NP floats
    float* pavg = ws + NP;  // NP floats (must follow pmax: conv indexes ch*NP)

    pool_kernel<<<NP / 4 / 256, 256, 0, stream>>>(x, pmax, pavg);
    conv_mul_kernel<<<2 * 16 * 16, 256, 0, stream>>>(pmax, w, x, out);
}